// Round 1
// 475.137 us; speedup vs baseline: 1.0456x; 1.0456x over previous
//
#include <hip/hip_runtime.h>

typedef unsigned short ushort_t;
typedef __attribute__((ext_vector_type(8))) __bf16 bf16x8;
typedef __attribute__((ext_vector_type(4))) float f32x4;

#define SEQ 8192
#define DIN 1024
#define DOUT 1024

// epilogue output modes
#define OM_BF16 0
#define OM_EXP  2   // bf16 exp2(scale*acc) store + per-block partial row-sums -> rsp
#define OM_NORM 3   // f32 store of acc * invrs[row]

__device__ __forceinline__ ushort_t f2bf(float f) {
  union { float f; unsigned u; } c; c.f = f;
  unsigned u = c.u;
  return (ushort_t)((u + 0x7fffu + ((u >> 16) & 1u)) >> 16);  // RNE
}

__device__ __forceinline__ void async16(ushort_t* lds, const ushort_t* g) {
  __builtin_amdgcn_global_load_lds(
      (__attribute__((address_space(1))) void*)g,
      (__attribute__((address_space(3))) void*)lds, 16, 0, 0);
}

template <int N>
__device__ __forceinline__ void waitv() {
  // counted vmcnt wait; "memory" clobber pins global_load_lds / ds_read ordering
  asm volatile("s_waitcnt vmcnt(%0)" :: "n"(N) : "memory");
}

// chunk-slot swizzle for BK=32 (4x 16B chunks/row): 2-way bank aliasing per
// 16-lane ds_read_b128 group (free per m136). Involution per row.
__device__ __forceinline__ int fsw(int row) { return (row ^ (row >> 2)) & 3; }

// ------- fused fp32 -> bf16 convert for x, Wq, Wk, Wv -------
__global__ __launch_bounds__(256) void cvt_all_kernel(
    const float* __restrict__ x, const float* __restrict__ wq,
    const float* __restrict__ wk, const float* __restrict__ wv,
    ushort_t* __restrict__ xb, ushort_t* __restrict__ wqkb,
    ushort_t* __restrict__ wvb) {
  int b = blockIdx.x;
  const float* src;
  ushort_t* dst;
  int idx;
  if (b < 8192) {
    src = x; dst = xb; idx = b * 256 + threadIdx.x;
  } else {
    int r = b - 8192;
    int w = r >> 10;
    idx = (r & 1023) * 256 + threadIdx.x;
    if (w == 0)      { src = wq; dst = wqkb; }
    else if (w == 1) { src = wk; dst = wqkb + DOUT * DIN; }
    else             { src = wv; dst = wvb; }
  }
  float4 f = ((const float4*)src)[idx];
  ushort4 o;
  o.x = f2bf(f.x); o.y = f2bf(f.y); o.z = f2bf(f.z); o.w = f2bf(f.w);
  ((ushort4*)dst)[idx] = o;
}

// ------- rowsum partials [32][SEQ] -> invrs[SEQ] = 1/sum -------
__global__ __launch_bounds__(256) void rowsum_inv_kernel(const float* __restrict__ rsp,
                                                         float* __restrict__ invrs) {
  int r = blockIdx.x * 256 + threadIdx.x;
  float s = 0.f;
  #pragma unroll
  for (int p2 = 0; p2 < 32; ++p2) s += rsp[p2 * SEQ + r];
  invrs[r] = 1.0f / s;
}

// ---------------- GEMM: C[M][N] = A[M][K] @ B[N][K]^T ----------------
// 256xBN tile (BN=256 or 128), K pipelined as a 4-deep ring of K=32 sub-tiles.
// 512 threads = 8 waves (2M x 4N); per-wave output 128 x BN/4 via 8xNIN
// mfma_f32_16x16x32_bf16, acc in VGPR (128 regs @BN=256).
// Schedule per sub-tile s (T2+T3+T4+T5 stack, derived from the 256^2 8-phase
// template): counted s_waitcnt vmcnt(2*LPG) -> raw s_barrier (NO drain; loads
// stay in flight across barriers) -> ds_read frags of ring[s&3] -> issue
// stage(s+3) into ring[(s+3)&3] -> setprio(1) MFMA cluster setprio(0).
// Ring-slot safety: stage(s+3) overwrites slot (s-1)&3 whose last readers
// finished before the top-of-iter-s barrier; readers of slot s&3 are gated by
// this thread's vmcnt (own loads landed) + barrier (all threads' loads landed).
// LDS swizzle: 16B chunk slot ^ fsw(row), applied on the GLOBAL source address
// (global_load_lds dest must stay lane-linear) and on the ds_read address.
template <int OUTMODE, int BN>
__global__ __launch_bounds__(512, 2) void gemm256(
    const ushort_t* __restrict__ A, const ushort_t* __restrict__ B,
    void* __restrict__ C, int lda, int ldb, int ldc, int K, float scale,
    float* __restrict__ rsp, const float* __restrict__ invrs) {
  constexpr int BKS = 32;               // K per sub-tile
  constexpr int NIN = BN / 64;          // B frags per wave (4 or 2)
  constexpr int NA = 2;                 // A staging loads / thread / stage
  constexpr int NB = BN * 4 / 512;      // B staging loads / thread / stage (2 or 1)
  constexpr int LPG = NA + NB;          // loads per stage group
  constexpr int AST = 256 * BKS;        // elements per A stage (8192)
  constexpr int BST = BN * BKS;         // elements per B stage
  __shared__ ushort_t As[4 * AST];      // 64 KB
  __shared__ ushort_t Bs[4 * BST];      // 64 or 32 KB

  const int t = threadIdx.x;
  const int lane = t & 63;
  const int wave = t >> 6;
  const int wr = wave >> 2, wc = wave & 3;
  const int quad = lane >> 4, r16 = lane & 15;

  // bijective XCD-aware swizzle (all grids here are multiples of 8 blocks);
  // consecutive remapped ids share mt (A row-strip) within one XCD's chunk.
  const int gx = gridDim.x;
  const int nwg = gx * gridDim.y;
  const int bid = blockIdx.y * gx + blockIdx.x;
  const int q8 = nwg >> 3;
  const int b2 = (bid & 7) * q8 + (bid >> 3);
  const int mt = b2 / gx;
  const int nt = b2 - mt * gx;
  const int rowBase = mt * 256;
  const int colBase = nt * BN;

  // per-thread 32-bit staging source offsets (elements), bumped BKS per stage
  unsigned offA[NA], offB[NB];
  #pragma unroll
  for (int i = 0; i < NA; ++i) {
    int c = t + i * 512, row = c >> 2, sl = c & 3;
    offA[i] = (unsigned)((rowBase + row) * lda + ((sl ^ fsw(row)) << 3));
  }
  #pragma unroll
  for (int i = 0; i < NB; ++i) {
    int c = t + i * 512, row = c >> 2, sl = c & 3;
    offB[i] = (unsigned)((colBase + row) * ldb + ((sl ^ fsw(row)) << 3));
  }

  f32x4 acc[8][NIN] = {};

  const int NS = K / BKS;   // 32 (K=1024) or 256 (K=8192); >= 3 always

  // prologue: issue stages 0,1,2
  #pragma unroll
  for (int s = 0; s < 3; ++s) {
    #pragma unroll
    for (int i = 0; i < NA; ++i) {
      async16(&As[s * AST + (t + i * 512) * 8], A + offA[i]); offA[i] += BKS;
    }
    #pragma unroll
    for (int i = 0; i < NB; ++i) {
      async16(&Bs[s * BST + (t + i * 512) * 8], B + offB[i]); offB[i] += BKS;
    }
  }

  for (int s = 0; s < NS; ++s) {
    // wait until this thread's stage-s loads landed (2 newer groups may fly)
    const int rem = NS - 1 - s;
    if (rem >= 2)      waitv<2 * LPG>();
    else if (rem == 1) waitv<LPG>();
    else               waitv<0>();
    __builtin_amdgcn_s_barrier();            // raw: no counter drain
    asm volatile("" ::: "memory");           // no ds_read hoists above barrier
    __builtin_amdgcn_sched_barrier(0);

    const ushort_t* as = &As[(s & 3) * AST];
    const ushort_t* bs = &Bs[(s & 3) * BST];
    bf16x8 af[8], bfr[NIN];
    #pragma unroll
    for (int mi = 0; mi < 8; ++mi) {
      int row = wr * 128 + mi * 16 + r16;
      int sl = quad ^ fsw(row);
      af[mi] = *(const bf16x8*)&as[(row * 4 + sl) * 8];
    }
    #pragma unroll
    for (int ni = 0; ni < NIN; ++ni) {
      int row = wc * (BN / 4) + ni * 16 + r16;
      int sl = quad ^ fsw(row);
      bfr[ni] = *(const bf16x8*)&bs[(row * 4 + sl) * 8];
    }

    // issue next stage while ds_reads / MFMAs run
    if (s + 3 < NS) {
      const int sb = (s + 3) & 3;
      #pragma unroll
      for (int i = 0; i < NA; ++i) {
        async16(&As[sb * AST + (t + i * 512) * 8], A + offA[i]); offA[i] += BKS;
      }
      #pragma unroll
      for (int i = 0; i < NB; ++i) {
        async16(&Bs[sb * BST + (t + i * 512) * 8], B + offB[i]); offB[i] += BKS;
      }
    }

    __builtin_amdgcn_s_setprio(1);
    #pragma unroll
    for (int mi = 0; mi < 8; ++mi)
      #pragma unroll
      for (int ni = 0; ni < NIN; ++ni)
        acc[mi][ni] = __builtin_amdgcn_mfma_f32_16x16x32_bf16(af[mi], bfr[ni],
                                                              acc[mi][ni], 0, 0, 0);
    __builtin_amdgcn_s_setprio(0);
    __builtin_amdgcn_sched_barrier(0);
  }

  // ---- epilogue: C/D layout col=lane&15, row=quad*4+reg ----
  float iv[8][4];
  if constexpr (OUTMODE == OM_NORM) {
    #pragma unroll
    for (int mi = 0; mi < 8; ++mi)
      #pragma unroll
      for (int r = 0; r < 4; ++r)
        iv[mi][r] = invrs[rowBase + wr * 128 + mi * 16 + quad * 4 + r];
  }

  float psum[8][4];
  if constexpr (OUTMODE == OM_EXP) {
    #pragma unroll
    for (int mi = 0; mi < 8; ++mi)
      #pragma unroll
      for (int r = 0; r < 4; ++r) psum[mi][r] = 0.f;
  }

  #pragma unroll
  for (int mi = 0; mi < 8; ++mi)
    #pragma unroll
    for (int ni = 0; ni < NIN; ++ni)
      #pragma unroll
      for (int r = 0; r < 4; ++r) {
        int grow = rowBase + wr * 128 + mi * 16 + quad * 4 + r;
        int gcol = colBase + wc * (BN / 4) + ni * 16 + r16;
        float a = acc[mi][ni][r];
        if constexpr (OUTMODE == OM_BF16) {
          ((ushort_t*)C)[(size_t)grow * ldc + gcol] = f2bf(a * scale);
        } else if constexpr (OUTMODE == OM_EXP) {
          float e = exp2f(a * scale);   // scale carries the log2(e) factor
          psum[mi][r] += e;
          ((ushort_t*)C)[(size_t)grow * ldc + gcol] = f2bf(e);
        } else {  // OM_NORM
          ((float*)C)[(size_t)grow * ldc + gcol] = a * iv[mi][r];
        }
      }

  if constexpr (OUTMODE == OM_EXP) {
    __syncthreads();                 // ring reads done before LDS reuse
    float* lds_rs = (float*)As;      // [4][256]
    #pragma unroll
    for (int mi = 0; mi < 8; ++mi)
      #pragma unroll
      for (int r = 0; r < 4; ++r) {
        float sv = psum[mi][r];
        sv += __shfl_xor(sv, 1, 64);
        sv += __shfl_xor(sv, 2, 64);
        sv += __shfl_xor(sv, 4, 64);
        sv += __shfl_xor(sv, 8, 64);
        if (r16 == 0)
          lds_rs[wc * 256 + wr * 128 + mi * 16 + quad * 4 + r] = sv;
      }
    __syncthreads();
    if (t < 256)
      rsp[(size_t)nt * SEQ + rowBase + t] =
          lds_rs[t] + lds_rs[256 + t] + lds_rs[512 + t] + lds_rs[768 + t];
  }
}

extern "C" void kernel_launch(void* const* d_in, const int* in_sizes, int n_in,
                              void* d_out, int out_size, void* d_ws, size_t ws_size,
                              hipStream_t stream) {
  const float* x  = (const float*)d_in[0];
  const float* Wq = (const float*)d_in[1];
  const float* Wk = (const float*)d_in[2];
  const float* Wv = (const float*)d_in[3];
  float* out = (float*)d_out;

  char* p = (char*)d_ws;
  ushort_t* xb   = (ushort_t*)p; p += (size_t)SEQ * DIN * 2;        // 16 MB
  ushort_t* wqkb = (ushort_t*)p; p += (size_t)2 * DOUT * DIN * 2;   //  4 MB (Wq|Wk)
  ushort_t* wvb  = (ushort_t*)p; p += (size_t)DOUT * DIN * 2;       //  2 MB
  ushort_t* qkb  = (ushort_t*)p; p += (size_t)SEQ * 2 * DOUT * 2;   // 32 MB ([S][2048], q|k)
  ushort_t* vtb  = (ushort_t*)p; p += (size_t)DOUT * SEQ * 2;       // 16 MB (v^T)
  float*    rsp  = (float*)p;    p += (size_t)64 * SEQ * 4;         //  2 MB partial rowsums
  float*    irs  = (float*)p;    p += (size_t)SEQ * 4;              // 32 KB 1/rowsum
  ushort_t* Sb   = (ushort_t*)p; p += (size_t)SEQ * SEQ * 2;        // 128 MB

  // fp32 -> bf16 for all four tensors (one launch)
  cvt_all_kernel<<<8192 + 3 * 1024, 256, 0, stream>>>(x, Wq, Wk, Wv, xb, wqkb, wvb);

  dim3 blk(512);
  // [q|k] = x @ [Wq|Wk]^T : M=8192, N=2048, K=1024 -> 32x8 = 256 blocks (1/CU)
  gemm256<OM_BF16, 256><<<dim3(2048 / 256, SEQ / 256), blk, 0, stream>>>(
      xb, wqkb, qkb, DIN, DIN, 2 * DOUT, DIN, 1.0f, nullptr, nullptr);

  // v^T = Wv @ x^T : M=1024, N=8192, K=1024 -> BN=128 keeps 4x64 = 256 blocks
  gemm256<OM_BF16, 128><<<dim3(SEQ / 128, DOUT / 256), blk, 0, stream>>>(
      wvb, xb, vtb, DIN, DIN, SEQ, DIN, 1.0f, nullptr, nullptr);

  // E = exp((q @ k^T)/32) via exp2, partial row sums -> rsp : 32x32 = 1024 blocks
  gemm256<OM_EXP, 256><<<dim3(SEQ / 256, SEQ / 256), blk, 0, stream>>>(
      qkb, qkb + DOUT, Sb, 2 * DOUT, 2 * DOUT, SEQ, DIN,
      0.03125f * 1.44269504f, rsp, nullptr);

  // invrs[r] = 1 / sum_p rsp[p][r]  (32 partial tiles now)
  rowsum_inv_kernel<<<SEQ / 256, 256, 0, stream>>>(rsp, irs);

  // out = (E @ v) * invrs : M=8192, N=1024, K=8192 -> BN=128 keeps 8x32 = 256 blocks
  gemm256<OM_NORM, 128><<<dim3(DOUT / 128, SEQ / 256), blk, 0, stream>>>(
      Sb, vtb, out, SEQ, SEQ, DOUT, SEQ, 1.0f, nullptr, irs);
}